// Round 15
// baseline (54.560 us; speedup 1.0000x reference)
//
#include <hip/hip_runtime.h>

#define B 256
#define K 32
#define M 64
#define MN 256
#define E 128
#define H 128
#define Q 128
#define NSLOT 258   // NNODES+2

typedef __attribute__((ext_vector_type(8))) short short8;
typedef __attribute__((ext_vector_type(4))) float f32x4;
typedef __attribute__((ext_vector_type(16))) float f32x16;

__device__ __forceinline__ float lrelu(float x){ return x >= 0.f ? x : 0.01f*x; }

// fp32 -> bf16 RTNE
__device__ __forceinline__ unsigned short f2bf(float f){
    unsigned int u = __float_as_uint(f);
    unsigned int r = u + 0x7FFFu + ((u >> 16) & 1u);
    return (unsigned short)(r >> 16);
}

// load 8 consecutive fp32 and pack to bf16 short8
__device__ __forceinline__ short8 f8_from(const float* __restrict__ p){
    float4 u = *(const float4*)p;
    float4 v = *(const float4*)(p + 4);
    short8 s;
    s[0]=(short)f2bf(u.x); s[1]=(short)f2bf(u.y); s[2]=(short)f2bf(u.z); s[3]=(short)f2bf(u.w);
    s[4]=(short)f2bf(v.x); s[5]=(short)f2bf(v.y); s[6]=(short)f2bf(v.z); s[7]=(short)f2bf(v.w);
    return s;
}

// =====================================================================
// K_FRONT roles (by blockIdx):
//  blk <  256 : init[b] + wninit[b]
//  blk <  512 : map[b]  (+ blk==256 zeroes zrow)
//  blk <  704 : Wf32 32x32-frag-order swizzle of candidate_W (49152)
//  blk <  832 : Wcatf frag-order swizzle (32768; ks 4..7 = hW)
//  blk <  848 : P-build: P = rel_emb @ passW[:,H:]^T, frag-order Pf
//  else (2048): hist role: 4 bk per block
// =====================================================================
__global__ void k_front(const int* __restrict__ aims, const int* __restrict__ nbr_nodes,
                        const int* __restrict__ nbr_rels, const int* __restrict__ nbr_num,
                        const int* __restrict__ start_ent, const int* __restrict__ node_pos,
                        const float* __restrict__ ent_emb, const float* __restrict__ rel_emb,
                        const float* __restrict__ hW, const float* __restrict__ hb,
                        const float* __restrict__ passW, const float* __restrict__ candW,
                        float* __restrict__ ab, int* __restrict__ map,
                        float* __restrict__ init_out, float* __restrict__ wninit_out,
                        unsigned short* __restrict__ Wf32, unsigned short* __restrict__ Wcatf,
                        unsigned short* __restrict__ Pf,
                        unsigned short* __restrict__ XhG, unsigned short* __restrict__ XaG,
                        float* __restrict__ zrow){
    int blk = blockIdx.x, t = threadIdx.x;
    __shared__ float e[128];
    __shared__ float si[128];
    __shared__ unsigned int hist[4][512];
    __shared__ float sden[4];

    if (blk >= 848) {
        // ---------------- hist role: 4 bk per block ----------------
        int hb4 = blk - 848;
        for (int i = t; i < 2048; i += 256) ((unsigned int*)hist)[i] = 0u;
        __syncthreads();
        int w = t >> 6, lane = t & 63;
        int bk = hb4*4 + w;
        int num = nbr_num[bk];
        int nr  = nbr_rels[(long)bk*M + lane];
        int nn  = nbr_nodes[(long)bk*M + lane];
        unsigned long long mask = __ballot((lane < num) && (nn == 0));
        int c0 = (int)__popcll(mask);
        float denom = (float)(num > 0 ? num : 1);
        if (lane < num) atomicAdd(&hist[w][nr], 1u);
        float2 av = *(const float2*)&ent_emb[(long)aims[bk]*E + lane*2];
        ushort2 ap; ap.x = f2bf(av.x); ap.y = f2bf(av.y);
        *(ushort2*)&XaG[(long)bk*128 + lane*2] = ap;
        if (lane == 0) {
            ab[bk*2+0] = (float)c0 / denom;
            ab[bk*2+1] = (float)num / denom;
            sden[w] = 1.f / denom;
        }
        __syncthreads();
        for (int i = t; i < 2048; i += 256) {
            int w2 = i >> 9, r = i & 511;
            float v = (float)hist[w2][r] * sden[w2];
            XhG[((long)(hb4*4 + w2))*512 + r] = f2bf(v);
        }
        return;
    }

    int pb = blk;
    if (pb < 256) {
        int b = pb;
        if (t < 128) e[t] = ent_emb[(long)start_ent[b]*E + t];
        __syncthreads();
        if (t < 128) {
            float acc = hb[t];
            #pragma unroll 8
            for (int j=0;j<E;j++) acc += hW[t*E+j]*e[j];
            float v = lrelu(acc);
            si[t] = v;
            init_out[b*H+t] = v;
        }
        __syncthreads();
        if (t < 128) {
            float acc2 = 0.f;
            #pragma unroll 8
            for (int j=0;j<H;j++) acc2 += passW[t*(H+E)+j]*si[j];
            wninit_out[b*H+t] = acc2;
        }
    } else if (pb < 512) {
        int b = pb - 256;
        for (int i=t;i<NSLOT;i+=256) map[b*NSLOT+i] = -2;
        __syncthreads();
        if (t==0) map[b*NSLOT+0] = -1;
        __syncthreads();
        if (t<K) map[b*NSLOT + node_pos[b*K+t]] = t;
        if (pb == 256 && t < 128) zrow[t] = 0.f;
    } else if (pb < 704) {
        // Wf32: i = ((ct*24 + s)*64 + lane)*8 + j
        // row(h) = ct*32 + (lane&31); col(k) = s*16 + (lane>>5)*8 + j
        int i = (pb-512)*256 + t;       // < 49152
        int j = i & 7;
        int l = (i >> 3) & 63;
        int r = i >> 9;                 // 0..95
        int s = r % 24, ct = r / 24;
        int row = ct*32 + (l & 31);
        int col = s*16 + (l >> 5)*8 + j;
        Wf32[i] = f2bf(candW[row*384 + col]);
    } else if (pb < 832) {
        int i = (pb-704)*256 + t;       // < 32768
        int j = i & 7;
        int l = (i >> 3) & 63;
        int ct = (i >> 9) & 1;
        int r = i >> 10;                // 0..31
        int ks = r & 7, w = r >> 3;
        int row = w*32 + ct*16 + (l & 15);
        int col = ks*32 + (l >> 4)*8 + j;
        float v = (col < 128) ? passW[row*256 + 128 + col] : hW[row*128 + (col-128)];
        Wcatf[i] = f2bf(v);
    } else {
        // ---------------- P-build: 16 blocks ----------------
        int g = pb - 832;               // 0..15
        int w = t >> 6, lane = t & 63;
        int l16 = lane & 15, lhi = lane >> 4;
        int hbase = w*32;
        const short8 z8 = (short8){0,0,0,0,0,0,0,0};
        f32x4 acc[2][2];
        #pragma unroll
        for (int rt=0;rt<2;rt++)
            #pragma unroll
            for (int ct=0;ct<2;ct++)
                acc[rt][ct] = (f32x4){0.f,0.f,0.f,0.f};
        #pragma unroll
        for (int ks2 = 0; ks2 < 4; ks2++) {
            int kof = ks2*32 + lhi*8;
            int r0 = g*32 + l16, r1 = g*32 + 16 + l16;
            short8 a0 = (r0 < 500) ? f8_from(&rel_emb[(long)r0*E + kof]) : z8;
            short8 a1 = (r1 < 500) ? f8_from(&rel_emb[(long)r1*E + kof]) : z8;
            short8 b0 = f8_from(&passW[(long)(hbase + l16)*(H+E) + H + kof]);
            short8 b1 = f8_from(&passW[(long)(hbase + 16 + l16)*(H+E) + H + kof]);
            acc[0][0] = __builtin_amdgcn_mfma_f32_16x16x32_bf16(a0, b0, acc[0][0], 0, 0, 0);
            acc[0][1] = __builtin_amdgcn_mfma_f32_16x16x32_bf16(a0, b1, acc[0][1], 0, 0, 0);
            acc[1][0] = __builtin_amdgcn_mfma_f32_16x16x32_bf16(a1, b0, acc[1][0], 0, 0, 0);
            acc[1][1] = __builtin_amdgcn_mfma_f32_16x16x32_bf16(a1, b1, acc[1][1], 0, 0, 0);
        }
        #pragma unroll
        for (int rt=0; rt<2; rt++) {
            #pragma unroll
            for (int ct=0; ct<2; ct++) {
                #pragma unroll
                for (int i=0;i<4;i++) {
                    int rp = rt*16 + 4*lhi + i;
                    long idx = ((long)((w*16 + g)*2 + ct))*512 + (l16 + (rp>>3)*16)*8 + (rp & 7);
                    Pf[idx] = f2bf(acc[rt][ct][i]);
                }
            }
        }
    }
}

// =====================================================================
// K_B: upd GEMM (hist@P^T + aimE@hW^T) + fused state/thresh (r13/r14)
// =====================================================================
__global__ void k_updg(const unsigned short* __restrict__ XhG,
                       const unsigned short* __restrict__ XaG,
                       const float* __restrict__ ab,
                       const unsigned short* __restrict__ Wcatf,
                       const unsigned short* __restrict__ Pf,
                       const float* __restrict__ hb_, const float* __restrict__ passb,
                       const float* __restrict__ wninit,
                       const int* __restrict__ currents, const int* __restrict__ map,
                       const float* __restrict__ init, const float* __restrict__ query,
                       const float* __restrict__ nW, const float* __restrict__ nb_,
                       const float* __restrict__ gW, const float* __restrict__ gb,
                       float* __restrict__ upd, float* __restrict__ state,
                       float* __restrict__ out){
    int b = blockIdx.x;
    int t = threadIdx.x;          // 0..255
    __shared__ __align__(16) unsigned short Xh[32][520];
    __shared__ __align__(16) unsigned short Xa[32][136];
    __shared__ float wni[128];
    __shared__ float sab[64];
    __shared__ float cc[H+Q];
    __shared__ float wsum[2];
    #pragma unroll
    for (int it = 0; it < 8; it++) {
        int idx = it*256 + t;
        int r = idx >> 6;
        int cg = (idx & 63) * 8;
        *(short8*)&Xh[r][cg] = *(const short8*)&XhG[((long)b*32 + r)*512 + cg];
    }
    #pragma unroll
    for (int it = 0; it < 2; it++) {
        int idx = it*256 + t;
        int r = idx >> 4;
        int cg = (idx & 15) * 8;
        *(short8*)&Xa[r][cg] = *(const short8*)&XaG[((long)b*32 + r)*128 + cg];
    }
    if (t < 128) wni[t] = wninit[b*128 + t];
    else if (t < 192) sab[t-128] = ab[b*64 + (t-128)];

    int w    = t >> 6;
    int lane = t & 63;
    int l16  = lane & 15;
    int lhi  = lane >> 4;
    int hbase = w*32;
    int mvc = map[b*NSLOT + currents[b]];
    __syncthreads();

    f32x4 acc[2][2];
    #pragma unroll
    for (int rt=0;rt<2;rt++)
        #pragma unroll
        for (int ct=0;ct<2;ct++)
            acc[rt][ct] = (f32x4){0.f,0.f,0.f,0.f};

    #pragma unroll 4
    for (int ks = 0; ks < 16; ks++) {
        int kof = ks*32 + lhi*8;
        short8 a0 = *(const short8*)&Xh[l16][kof];
        short8 a1 = *(const short8*)&Xh[16 + l16][kof];
        short8 b0 = *(const short8*)&Pf[(((long)(w*16+ks)*2 + 0)*64 + lane)*8];
        short8 b1 = *(const short8*)&Pf[(((long)(w*16+ks)*2 + 1)*64 + lane)*8];
        acc[0][0] = __builtin_amdgcn_mfma_f32_16x16x32_bf16(a0, b0, acc[0][0], 0, 0, 0);
        acc[0][1] = __builtin_amdgcn_mfma_f32_16x16x32_bf16(a0, b1, acc[0][1], 0, 0, 0);
        acc[1][0] = __builtin_amdgcn_mfma_f32_16x16x32_bf16(a1, b0, acc[1][0], 0, 0, 0);
        acc[1][1] = __builtin_amdgcn_mfma_f32_16x16x32_bf16(a1, b1, acc[1][1], 0, 0, 0);
    }
    #pragma unroll
    for (int ks2 = 0; ks2 < 4; ks2++) {
        int kof = ks2*32 + lhi*8;
        short8 a0 = *(const short8*)&Xa[l16][kof];
        short8 a1 = *(const short8*)&Xa[16 + l16][kof];
        short8 b0 = *(const short8*)&Wcatf[((((w*8 + 4 + ks2)*2 + 0)*64) + lane)*8];
        short8 b1 = *(const short8*)&Wcatf[((((w*8 + 4 + ks2)*2 + 1)*64) + lane)*8];
        acc[0][0] = __builtin_amdgcn_mfma_f32_16x16x32_bf16(a0, b0, acc[0][0], 0, 0, 0);
        acc[0][1] = __builtin_amdgcn_mfma_f32_16x16x32_bf16(a0, b1, acc[0][1], 0, 0, 0);
        acc[1][0] = __builtin_amdgcn_mfma_f32_16x16x32_bf16(a1, b0, acc[1][0], 0, 0, 0);
        acc[1][1] = __builtin_amdgcn_mfma_f32_16x16x32_bf16(a1, b1, acc[1][1], 0, 0, 0);
    }

    int h0 = hbase + l16, h1 = hbase + 16 + l16;
    float hb0 = hb_[h0], hb1 = hb_[h1];
    float pb0 = passb[h0], pb1 = passb[h1];
    float w0 = wni[h0],  w1 = wni[h1];

    if (t < 128) {
        cc[t] = (mvc == -1) ? init[b*H + t] : 0.f;
        cc[H+t] = query[b*Q + t];
    }

    float uv[2][2][4];
    #pragma unroll
    for (int rt=0; rt<2; rt++) {
        #pragma unroll
        for (int i=0;i<4;i++) {
            int r = rt*16 + 4*lhi + i;
            float al = sab[r*2], be = sab[r*2+1];
            float v0 = lrelu(hb0 + al*w0 + be*pb0 + acc[rt][0][i]);
            float v1 = lrelu(hb1 + al*w1 + be*pb1 + acc[rt][1][i]);
            uv[rt][0][i] = v0; uv[rt][1][i] = v1;
            upd[((long)b*32 + r)*128 + h0] = v0;
            upd[((long)b*32 + r)*128 + h1] = v1;
        }
    }
    __syncthreads();
    if (mvc >= 0) {
        #pragma unroll
        for (int rt=0; rt<2; rt++) {
            #pragma unroll
            for (int i=0;i<4;i++) {
                int r = rt*16 + 4*lhi + i;
                if (r == mvc) { cc[h0] = uv[rt][0][i]; cc[h1] = uv[rt][1][i]; }
            }
        }
    }
    __syncthreads();

    if (t < 128) {
        float sacc = nb_[t];
        #pragma unroll 8
        for (int j=0;j<H+Q;j++) sacc += nW[t*(H+Q)+j]*cc[j];
        state[b*H+t] = lrelu(sacc);
        float tv = gW[t]*cc[t] + gW[H+t]*cc[H+t];
        for (int off=32; off>0; off>>=1) tv += __shfl_down(tv, off);
        if ((t&63)==0) wsum[t>>6] = tv;
    }
    __syncthreads();
    if (t==0) out[b*(MN+1) + MN] = wsum[0] + wsum[1] + gb[0];
}

// =====================================================================
// K_D: candidate linear — WAVE-AUTONOMOUS 32-cand tiles, 32x32x16 MFMA.
// No LDS, no barriers, no atomics. All 32 cand index chains resolve in
// parallel across lanes; A-frags straight from gathered rows (fp32->bf16
// in-register); B streams from 32x32-frag-order Wf32.
// =====================================================================
__global__ __launch_bounds__(256, 3)
void k_cand(const int* __restrict__ cnodes, const int* __restrict__ cents,
            const int* __restrict__ crels, const int* __restrict__ cmask,
            const int* __restrict__ map,
            const float* __restrict__ init, const float* __restrict__ upd,
            const float* __restrict__ ent_emb, const float* __restrict__ rel_emb,
            const unsigned short* __restrict__ Wf32, const float* __restrict__ cb,
            const float* __restrict__ state, const float* __restrict__ zrow,
            float* __restrict__ out){
    int blk = blockIdx.x;          // 0..511
    int t = threadIdx.x;
    int w = t >> 6, lane = t & 63;
    int tile = blk*4 + w;          // 0..2047
    int b  = tile >> 3;
    int c0 = (tile & 7) * 32;
    int l32 = lane & 31;
    int kh  = (lane >> 5) * 8;     // k sub-chunk within each 16

    // ---- per-lane candidate resolution (all 32 in parallel) ----
    int row = b*MN + c0 + l32;
    int cn = cnodes[row];
    int ce = cents[row];
    int cr = crels[row];
    int mv = map[b*NSLOT + cn];
    const float* pn = zrow;
    pn = (mv == -1) ? (init + (long)b*H) : pn;
    pn = (mv >= 0)  ? (upd + ((long)b*K + mv)*H) : pn;
    const float* pe = ent_emb + (long)ce*E;
    const float* pr = rel_emb + (long)cr*E;

    f32x16 acc[4];
    #pragma unroll
    for (int ct=0; ct<4; ct++)
        #pragma unroll
        for (int i=0;i<16;i++) acc[ct][i] = 0.f;

    // ---- K loop: 24 steps of k=16; A row = cand l32, k = s*16 + kh ----
    #pragma unroll
    for (int s = 0; s < 24; s++) {
        const float* src = (s < 8)  ? (pn + s*16 + kh)
                         : (s < 16) ? (pe + (s-8)*16 + kh)
                                    : (pr + (s-16)*16 + kh);
        short8 a = f8_from(src);
        #pragma unroll
        for (int ct = 0; ct < 4; ct++) {
            short8 bfr = *(const short8*)&Wf32[(((long)(ct*24 + s)*64) + lane)*8];
            acc[ct] = __builtin_amdgcn_mfma_f32_32x32x16_bf16(a, bfr, acc[ct], 0, 0, 0);
        }
    }

    // ---- epilogue: ps[r] = sum_h lrelu(acc+cb)*state; reduce over 32 cols ----
    float ps[16];
    #pragma unroll
    for (int r=0;r<16;r++) ps[r] = 0.f;
    #pragma unroll
    for (int ct=0; ct<4; ct++) {
        float st  = state[b*H + ct*32 + l32];
        float cbv = cb[ct*32 + l32];
        #pragma unroll
        for (int r=0;r<16;r++)
            ps[r] += lrelu(acc[ct][r] + cbv) * st;
    }
    #pragma unroll
    for (int msk=1; msk<32; msk<<=1) {
        #pragma unroll
        for (int r=0;r<16;r++) ps[r] += __shfl_xor(ps[r], msk);
    }
    if (l32 == 0) {
        int hi4 = (lane >> 5) * 4;
        #pragma unroll
        for (int r=0;r<16;r++) {
            int crow = (r & 3) + 8*(r >> 2) + hi4;   // D row per m74/m101
            int orow = b*MN + c0 + crow;
            float s = ps[r] * 0.08838834764831845f;  // 1/sqrt(128)
            out[b*(MN+1) + c0 + crow] = cmask[orow] ? s : -100000.0f;
        }
    }
}

extern "C" void kernel_launch(void* const* d_in, const int* in_sizes, int n_in,
                              void* d_out, int out_size, void* d_ws, size_t ws_size,
                              hipStream_t stream){
    (void)in_sizes; (void)n_in; (void)out_size; (void)ws_size;
    const int* start_entities      = (const int*)d_in[0];
    const int* aims                = (const int*)d_in[1];
    const int* node_pos            = (const int*)d_in[2];
    const int* neighbor_nodes      = (const int*)d_in[3];
    const int* neighbor_relations  = (const int*)d_in[4];
    const int* neighbors_num       = (const int*)d_in[5];
    const int* currents            = (const int*)d_in[6];
    const int* candidate_nodes     = (const int*)d_in[7];
    const int* candidate_entities  = (const int*)d_in[8];
    const int* candidate_relations = (const int*)d_in[9];
    const int* candidate_masks     = (const int*)d_in[10];
    const float* entity_emb   = (const float*)d_in[11];
    const float* relation_emb = (const float*)d_in[12];
    const float* hidden_W     = (const float*)d_in[13];
    const float* hidden_b     = (const float*)d_in[14];
    const float* pass_W       = (const float*)d_in[15];
    const float* pass_b       = (const float*)d_in[16];
    const float* nexthop_W    = (const float*)d_in[17];
    const float* nexthop_b    = (const float*)d_in[18];
    const float* candidate_W  = (const float*)d_in[19];
    const float* candidate_b  = (const float*)d_in[20];
    const float* gate_W       = (const float*)d_in[21];
    const float* gate_b       = (const float*)d_in[22];
    const float* query        = (const float*)d_in[23];
    float* out = (float*)d_out;

    float* ws     = (float*)d_ws;
    float* init   = ws;                        // B*H
    float* wninit = init + B*H;                // B*H
    float* upd    = wninit + B*H;              // B*K*H
    float* state  = upd + (long)B*K*H;         // B*H
    float* ab     = state + B*H;               // B*K*2
    float* zrow   = ab + B*K*2;                // 128
    int*   map    = (int*)(zrow + 128);        // B*NSLOT
    unsigned short* Wf32  = (unsigned short*)(map + B*NSLOT);  // 49152
    unsigned short* Wcatf = Wf32 + 49152;                       // 32768
    unsigned short* Pf    = Wcatf + 32768;                      // 65536
    unsigned short* XhG   = Pf + 65536;                         // B*K*512
    unsigned short* XaG   = XhG + (long)B*K*512;                // B*K*128

    k_front<<<848 + (B*K)/4, 256, 0, stream>>>(aims, neighbor_nodes, neighbor_relations,
                                               neighbors_num, start_entities, node_pos,
                                               entity_emb, relation_emb,
                                               hidden_W, hidden_b, pass_W, candidate_W,
                                               ab, map, init, wninit, Wf32, Wcatf,
                                               Pf, XhG, XaG, zrow);
    k_updg<<<B, 256, 0, stream>>>(XhG, XaG, ab, Wcatf, Pf, hidden_b, pass_b, wninit,
                                  currents, map, init, query,
                                  nexthop_W, nexthop_b, gate_W, gate_b,
                                  upd, state, out);
    k_cand<<<(B*(MN/32))/4, 256, 0, stream>>>(candidate_nodes, candidate_entities,
                                              candidate_relations, candidate_masks,
                                              map, init, upd, entity_emb, relation_emb,
                                              Wf32, candidate_b, state, zrow, out);
}

// Round 16
// 49.582 us; speedup vs baseline: 1.1004x; 1.1004x over previous
//
#include <hip/hip_runtime.h>

#define B 256
#define K 32
#define M 64
#define MN 256
#define E 128
#define H 128
#define Q 128
#define NSLOT 258   // NNODES+2
#define CTILE 32
#define XPAD 392    // 384 + 8 bf16 pad

typedef __attribute__((ext_vector_type(8))) short short8;
typedef __attribute__((ext_vector_type(4))) short short4b;
typedef __attribute__((ext_vector_type(4))) float f32x4;

__device__ __forceinline__ float lrelu(float x){ return x >= 0.f ? x : 0.01f*x; }

// fp32 -> bf16 RTNE
__device__ __forceinline__ unsigned short f2bf(float f){
    unsigned int u = __float_as_uint(f);
    unsigned int r = u + 0x7FFFu + ((u >> 16) & 1u);
    return (unsigned short)(r >> 16);
}

__device__ __forceinline__ short4b pack4(float4 v){
    short4b r;
    r.x = (short)f2bf(v.x); r.y = (short)f2bf(v.y);
    r.z = (short)f2bf(v.z); r.w = (short)f2bf(v.w);
    return r;
}

// load 8 consecutive fp32 and pack to bf16 short8
__device__ __forceinline__ short8 f8_from(const float* __restrict__ p){
    float4 u = *(const float4*)p;
    float4 v = *(const float4*)(p + 4);
    short8 s;
    s[0]=(short)f2bf(u.x); s[1]=(short)f2bf(u.y); s[2]=(short)f2bf(u.z); s[3]=(short)f2bf(u.w);
    s[4]=(short)f2bf(v.x); s[5]=(short)f2bf(v.y); s[6]=(short)f2bf(v.z); s[7]=(short)f2bf(v.w);
    return s;
}

// =====================================================================
// K_FRONT roles (by blockIdx) — r14 version:
//  blk <  256 : init[b] + wninit[b]
//  blk <  512 : map[b]  (+ blk==256 zeroes zrow)
//  blk <  704 : Wf  frag-order swizzle   (49152 elems)
//  blk <  832 : Wcatf frag-order swizzle (32768 elems; ks 4..7 = hW)
//  blk <  848 : P-build: P = rel_emb @ passW[:,H:]^T, frag-order Pf
//  else (2048): hist role: 4 bk per block
// =====================================================================
__global__ void k_front(const int* __restrict__ aims, const int* __restrict__ nbr_nodes,
                        const int* __restrict__ nbr_rels, const int* __restrict__ nbr_num,
                        const int* __restrict__ start_ent, const int* __restrict__ node_pos,
                        const float* __restrict__ ent_emb, const float* __restrict__ rel_emb,
                        const float* __restrict__ hW, const float* __restrict__ hb,
                        const float* __restrict__ passW, const float* __restrict__ candW,
                        float* __restrict__ ab, int* __restrict__ map,
                        float* __restrict__ init_out, float* __restrict__ wninit_out,
                        unsigned short* __restrict__ Wf, unsigned short* __restrict__ Wcatf,
                        unsigned short* __restrict__ Pf,
                        unsigned short* __restrict__ XhG, unsigned short* __restrict__ XaG,
                        float* __restrict__ zrow){
    int blk = blockIdx.x, t = threadIdx.x;
    __shared__ float e[128];
    __shared__ float si[128];
    __shared__ unsigned int hist[4][512];
    __shared__ float sden[4];

    if (blk >= 848) {
        // ---------------- hist role: 4 bk per block ----------------
        int hb4 = blk - 848;
        for (int i = t; i < 2048; i += 256) ((unsigned int*)hist)[i] = 0u;
        __syncthreads();
        int w = t >> 6, lane = t & 63;
        int bk = hb4*4 + w;
        int num = nbr_num[bk];
        int nr  = nbr_rels[(long)bk*M + lane];
        int nn  = nbr_nodes[(long)bk*M + lane];
        unsigned long long mask = __ballot((lane < num) && (nn == 0));
        int c0 = (int)__popcll(mask);
        float denom = (float)(num > 0 ? num : 1);
        if (lane < num) atomicAdd(&hist[w][nr], 1u);
        float2 av = *(const float2*)&ent_emb[(long)aims[bk]*E + lane*2];
        ushort2 ap; ap.x = f2bf(av.x); ap.y = f2bf(av.y);
        *(ushort2*)&XaG[(long)bk*128 + lane*2] = ap;
        if (lane == 0) {
            ab[bk*2+0] = (float)c0 / denom;
            ab[bk*2+1] = (float)num / denom;
            sden[w] = 1.f / denom;
        }
        __syncthreads();
        for (int i = t; i < 2048; i += 256) {
            int w2 = i >> 9, r = i & 511;
            float v = (float)hist[w2][r] * sden[w2];
            XhG[((long)(hb4*4 + w2))*512 + r] = f2bf(v);
        }
        return;
    }

    int pb = blk;
    if (pb < 256) {
        int b = pb;
        if (t < 128) e[t] = ent_emb[(long)start_ent[b]*E + t];
        __syncthreads();
        if (t < 128) {
            float acc = hb[t];
            #pragma unroll 8
            for (int j=0;j<E;j++) acc += hW[t*E+j]*e[j];
            float v = lrelu(acc);
            si[t] = v;
            init_out[b*H+t] = v;
        }
        __syncthreads();
        if (t < 128) {
            float acc2 = 0.f;
            #pragma unroll 8
            for (int j=0;j<H;j++) acc2 += passW[t*(H+E)+j]*si[j];
            wninit_out[b*H+t] = acc2;
        }
    } else if (pb < 512) {
        int b = pb - 256;
        for (int i=t;i<NSLOT;i+=256) map[b*NSLOT+i] = -2;
        __syncthreads();
        if (t==0) map[b*NSLOT+0] = -1;
        __syncthreads();
        if (t<K) map[b*NSLOT + node_pos[b*K+t]] = t;
        if (pb == 256 && t < 128) zrow[t] = 0.f;   // zero row for branch-free staging
    } else if (pb < 704) {
        int i = (pb-512)*256 + t;       // < 49152
        int j = i & 7;
        int l = (i >> 3) & 63;
        int ct = (i >> 9) & 1;
        int r = i >> 10;                // 0..47
        int ks = r % 12, w = r / 12;
        int row = w*32 + ct*16 + (l & 15);
        int col = ks*32 + (l >> 4)*8 + j;
        Wf[i] = f2bf(candW[row*384 + col]);
    } else if (pb < 832) {
        int i = (pb-704)*256 + t;       // < 32768
        int j = i & 7;
        int l = (i >> 3) & 63;
        int ct = (i >> 9) & 1;
        int r = i >> 10;                // 0..31
        int ks = r & 7, w = r >> 3;
        int row = w*32 + ct*16 + (l & 15);
        int col = ks*32 + (l >> 4)*8 + j;
        float v = (col < 128) ? passW[row*256 + 128 + col] : hW[row*128 + (col-128)];
        Wcatf[i] = f2bf(v);
    } else {
        // ---------------- P-build: 16 blocks ----------------
        int g = pb - 832;               // 0..15
        int w = t >> 6, lane = t & 63;
        int l16 = lane & 15, lhi = lane >> 4;
        int hbase = w*32;
        const short8 z8 = (short8){0,0,0,0,0,0,0,0};
        f32x4 acc[2][2];
        #pragma unroll
        for (int rt=0;rt<2;rt++)
            #pragma unroll
            for (int ct=0;ct<2;ct++)
                acc[rt][ct] = (f32x4){0.f,0.f,0.f,0.f};
        #pragma unroll
        for (int ks2 = 0; ks2 < 4; ks2++) {
            int kof = ks2*32 + lhi*8;
            int r0 = g*32 + l16, r1 = g*32 + 16 + l16;
            short8 a0 = (r0 < 500) ? f8_from(&rel_emb[(long)r0*E + kof]) : z8;
            short8 a1 = (r1 < 500) ? f8_from(&rel_emb[(long)r1*E + kof]) : z8;
            short8 b0 = f8_from(&passW[(long)(hbase + l16)*(H+E) + H + kof]);
            short8 b1 = f8_from(&passW[(long)(hbase + 16 + l16)*(H+E) + H + kof]);
            acc[0][0] = __builtin_amdgcn_mfma_f32_16x16x32_bf16(a0, b0, acc[0][0], 0, 0, 0);
            acc[0][1] = __builtin_amdgcn_mfma_f32_16x16x32_bf16(a0, b1, acc[0][1], 0, 0, 0);
            acc[1][0] = __builtin_amdgcn_mfma_f32_16x16x32_bf16(a1, b0, acc[1][0], 0, 0, 0);
            acc[1][1] = __builtin_amdgcn_mfma_f32_16x16x32_bf16(a1, b1, acc[1][1], 0, 0, 0);
        }
        #pragma unroll
        for (int rt=0; rt<2; rt++) {
            #pragma unroll
            for (int ct=0; ct<2; ct++) {
                #pragma unroll
                for (int i=0;i<4;i++) {
                    int rp = rt*16 + 4*lhi + i;
                    long idx = ((long)((w*16 + g)*2 + ct))*512 + (l16 + (rp>>3)*16)*8 + (rp & 7);
                    Pf[idx] = f2bf(acc[rt][ct][i]);
                }
            }
        }
    }
}

// =====================================================================
// K_B: upd GEMM (hist@P^T + aimE@hW^T) + fused state/thresh (r14)
// =====================================================================
__global__ void k_updg(const unsigned short* __restrict__ XhG,
                       const unsigned short* __restrict__ XaG,
                       const float* __restrict__ ab,
                       const unsigned short* __restrict__ Wcatf,
                       const unsigned short* __restrict__ Pf,
                       const float* __restrict__ hb_, const float* __restrict__ passb,
                       const float* __restrict__ wninit,
                       const int* __restrict__ currents, const int* __restrict__ map,
                       const float* __restrict__ init, const float* __restrict__ query,
                       const float* __restrict__ nW, const float* __restrict__ nb_,
                       const float* __restrict__ gW, const float* __restrict__ gb,
                       float* __restrict__ upd, float* __restrict__ state,
                       float* __restrict__ out){
    int b = blockIdx.x;
    int t = threadIdx.x;          // 0..255
    __shared__ __align__(16) unsigned short Xh[32][520];
    __shared__ __align__(16) unsigned short Xa[32][136];
    __shared__ float wni[128];
    __shared__ float sab[64];
    __shared__ float cc[H+Q];
    __shared__ float wsum[2];
    #pragma unroll
    for (int it = 0; it < 8; it++) {
        int idx = it*256 + t;
        int r = idx >> 6;
        int cg = (idx & 63) * 8;
        *(short8*)&Xh[r][cg] = *(const short8*)&XhG[((long)b*32 + r)*512 + cg];
    }
    #pragma unroll
    for (int it = 0; it < 2; it++) {
        int idx = it*256 + t;
        int r = idx >> 4;
        int cg = (idx & 15) * 8;
        *(short8*)&Xa[r][cg] = *(const short8*)&XaG[((long)b*32 + r)*128 + cg];
    }
    if (t < 128) wni[t] = wninit[b*128 + t];
    else if (t < 192) sab[t-128] = ab[b*64 + (t-128)];

    int w    = t >> 6;
    int lane = t & 63;
    int l16  = lane & 15;
    int lhi  = lane >> 4;
    int hbase = w*32;
    int mvc = map[b*NSLOT + currents[b]];
    __syncthreads();

    f32x4 acc[2][2];
    #pragma unroll
    for (int rt=0;rt<2;rt++)
        #pragma unroll
        for (int ct=0;ct<2;ct++)
            acc[rt][ct] = (f32x4){0.f,0.f,0.f,0.f};

    #pragma unroll 4
    for (int ks = 0; ks < 16; ks++) {
        int kof = ks*32 + lhi*8;
        short8 a0 = *(const short8*)&Xh[l16][kof];
        short8 a1 = *(const short8*)&Xh[16 + l16][kof];
        short8 b0 = *(const short8*)&Pf[(((long)(w*16+ks)*2 + 0)*64 + lane)*8];
        short8 b1 = *(const short8*)&Pf[(((long)(w*16+ks)*2 + 1)*64 + lane)*8];
        acc[0][0] = __builtin_amdgcn_mfma_f32_16x16x32_bf16(a0, b0, acc[0][0], 0, 0, 0);
        acc[0][1] = __builtin_amdgcn_mfma_f32_16x16x32_bf16(a0, b1, acc[0][1], 0, 0, 0);
        acc[1][0] = __builtin_amdgcn_mfma_f32_16x16x32_bf16(a1, b0, acc[1][0], 0, 0, 0);
        acc[1][1] = __builtin_amdgcn_mfma_f32_16x16x32_bf16(a1, b1, acc[1][1], 0, 0, 0);
    }
    #pragma unroll
    for (int ks2 = 0; ks2 < 4; ks2++) {
        int kof = ks2*32 + lhi*8;
        short8 a0 = *(const short8*)&Xa[l16][kof];
        short8 a1 = *(const short8*)&Xa[16 + l16][kof];
        short8 b0 = *(const short8*)&Wcatf[((((w*8 + 4 + ks2)*2 + 0)*64) + lane)*8];
        short8 b1 = *(const short8*)&Wcatf[((((w*8 + 4 + ks2)*2 + 1)*64) + lane)*8];
        acc[0][0] = __builtin_amdgcn_mfma_f32_16x16x32_bf16(a0, b0, acc[0][0], 0, 0, 0);
        acc[0][1] = __builtin_amdgcn_mfma_f32_16x16x32_bf16(a0, b1, acc[0][1], 0, 0, 0);
        acc[1][0] = __builtin_amdgcn_mfma_f32_16x16x32_bf16(a1, b0, acc[1][0], 0, 0, 0);
        acc[1][1] = __builtin_amdgcn_mfma_f32_16x16x32_bf16(a1, b1, acc[1][1], 0, 0, 0);
    }

    int h0 = hbase + l16, h1 = hbase + 16 + l16;
    float hb0 = hb_[h0], hb1 = hb_[h1];
    float pb0 = passb[h0], pb1 = passb[h1];
    float w0 = wni[h0],  w1 = wni[h1];

    if (t < 128) {
        cc[t] = (mvc == -1) ? init[b*H + t] : 0.f;
        cc[H+t] = query[b*Q + t];
    }

    float uv[2][2][4];
    #pragma unroll
    for (int rt=0; rt<2; rt++) {
        #pragma unroll
        for (int i=0;i<4;i++) {
            int r = rt*16 + 4*lhi + i;
            float al = sab[r*2], be = sab[r*2+1];
            float v0 = lrelu(hb0 + al*w0 + be*pb0 + acc[rt][0][i]);
            float v1 = lrelu(hb1 + al*w1 + be*pb1 + acc[rt][1][i]);
            uv[rt][0][i] = v0; uv[rt][1][i] = v1;
            upd[((long)b*32 + r)*128 + h0] = v0;
            upd[((long)b*32 + r)*128 + h1] = v1;
        }
    }
    __syncthreads();
    if (mvc >= 0) {
        #pragma unroll
        for (int rt=0; rt<2; rt++) {
            #pragma unroll
            for (int i=0;i<4;i++) {
                int r = rt*16 + 4*lhi + i;
                if (r == mvc) { cc[h0] = uv[rt][0][i]; cc[h1] = uv[rt][1][i]; }
            }
        }
    }
    __syncthreads();

    if (t < 128) {
        float sacc = nb_[t];
        #pragma unroll 8
        for (int j=0;j<H+Q;j++) sacc += nW[t*(H+Q)+j]*cc[j];
        state[b*H+t] = lrelu(sacc);
        float tv = gW[t]*cc[t] + gW[H+t]*cc[H+t];
        for (int off=32; off>0; off>>=1) tv += __shfl_down(tv, off);
        if ((t&63)==0) wsum[t>>6] = tv;
    }
    __syncthreads();
    if (t==0) out[b*(MN+1) + MN] = wsum[0] + wsum[1] + gb[0];
}

// =====================================================================
// K_D: candidate linear, 2048 blocks x 32 cands; INLINE per-thread
// resolution (no resolve barrier / LDS roundtrip) + branch-free batch
// staging (12 loads in flight), streamed weights, fused score.
// =====================================================================
__global__ void k_cand(const int* __restrict__ cnodes, const int* __restrict__ cents,
                       const int* __restrict__ crels, const int* __restrict__ cmask,
                       const int* __restrict__ map,
                       const float* __restrict__ init, const float* __restrict__ upd,
                       const float* __restrict__ ent_emb, const float* __restrict__ rel_emb,
                       const unsigned short* __restrict__ Wf, const float* __restrict__ cb,
                       const float* __restrict__ state, const float* __restrict__ zrow,
                       float* __restrict__ out){
    int blk = blockIdx.x;          // 0..2047
    int b  = blk >> 3;
    int c0 = (blk & 7) * CTILE;
    int t  = threadIdx.x;          // 0..255

    __shared__ __align__(16) unsigned short Xb[CTILE][XPAD];
    __shared__ float sscore[4][CTILE];

    // ---- inline resolution + branch-free batch staging ----
    {
        int c8 = t >> 5;           // cand sub-slot 0..7
        int q  = t & 31;           // float4 index
        // 12 independent index loads (same addr across q-lanes -> broadcast)
        int cn[4], ce[4], cr[4];
        #pragma unroll
        for (int i = 0; i < 4; i++) {
            int row = b*MN + c0 + i*8 + c8;
            cn[i] = cnodes[row];
            ce[i] = cents[row];
            cr[i] = crels[row];
        }
        // 4 dependent map loads
        int mv[4];
        #pragma unroll
        for (int i = 0; i < 4; i++) mv[i] = map[b*NSLOT + cn[i]];
        // 12 row loads, all in flight
        const float* pn[4]; const float* pe[4]; const float* pr[4];
        #pragma unroll
        for (int i = 0; i < 4; i++) {
            const float* bs = zrow;                                  // mv == -2
            bs = (mv[i] == -1) ? (init + (long)b*H) : bs;
            bs = (mv[i] >= 0)  ? (upd + ((long)b*K + mv[i])*H) : bs;
            pn[i] = bs + q*4;
            pe[i] = ent_emb + (long)ce[i]*E + q*4;
            pr[i] = rel_emb + (long)cr[i]*E + q*4;
        }
        float4 vn[4], ve[4], vr[4];
        #pragma unroll
        for (int i = 0; i < 4; i++) vn[i] = *(const float4*)pn[i];
        #pragma unroll
        for (int i = 0; i < 4; i++) ve[i] = *(const float4*)pe[i];
        #pragma unroll
        for (int i = 0; i < 4; i++) vr[i] = *(const float4*)pr[i];
        #pragma unroll
        for (int i = 0; i < 4; i++) {
            int cl = i*8 + c8;
            *(short4b*)&Xb[cl][q*4]       = pack4(vn[i]);
            *(short4b*)&Xb[cl][128 + q*4] = pack4(ve[i]);
            *(short4b*)&Xb[cl][256 + q*4] = pack4(vr[i]);
        }
    }

    int w    = t >> 6;
    int lane = t & 63;
    int l16  = lane & 15;
    int lhi  = lane >> 4;

    float s0 = state[b*H + w*32 + l16];
    float s1 = state[b*H + w*32 + 16 + l16];
    float cb0 = cb[w*32 + l16];
    float cb1 = cb[w*32 + 16 + l16];
    __syncthreads();

    f32x4 acc[2][2];
    #pragma unroll
    for (int rt=0;rt<2;rt++)
        #pragma unroll
        for (int ct=0;ct<2;ct++)
            acc[rt][ct] = (f32x4){0.f,0.f,0.f,0.f};

    #pragma unroll
    for (int ks = 0; ks < 12; ks++) {
        int kof = ks*32 + lhi*8;
        short8 b0 = *(const short8*)&Wf[((((w*12+ks)*2+0)*64) + lane)*8];
        short8 b1 = *(const short8*)&Wf[((((w*12+ks)*2+1)*64) + lane)*8];
        short8 a0 = *(const short8*)&Xb[l16][kof];
        short8 a1 = *(const short8*)&Xb[16 + l16][kof];
        acc[0][0] = __builtin_amdgcn_mfma_f32_16x16x32_bf16(a0, b0, acc[0][0], 0, 0, 0);
        acc[0][1] = __builtin_amdgcn_mfma_f32_16x16x32_bf16(a0, b1, acc[0][1], 0, 0, 0);
        acc[1][0] = __builtin_amdgcn_mfma_f32_16x16x32_bf16(a1, b0, acc[1][0], 0, 0, 0);
        acc[1][1] = __builtin_amdgcn_mfma_f32_16x16x32_bf16(a1, b1, acc[1][1], 0, 0, 0);
    }

    #pragma unroll
    for (int rt=0; rt<2; rt++) {
        float ps[4];
        #pragma unroll
        for (int i=0;i<4;i++)
            ps[i] = lrelu(acc[rt][0][i] + cb0)*s0 + lrelu(acc[rt][1][i] + cb1)*s1;
        #pragma unroll
        for (int msk=1; msk<16; msk<<=1) {
            #pragma unroll
            for (int i=0;i<4;i++) ps[i] += __shfl_xor(ps[i], msk);
        }
        if (l16 == 0) {
            #pragma unroll
            for (int i=0;i<4;i++)
                sscore[w][rt*16 + 4*lhi + i] = ps[i];
        }
    }
    __syncthreads();

    if (t < CTILE) {
        int row = b*MN + c0 + t;
        float s = (sscore[0][t] + sscore[1][t] + sscore[2][t] + sscore[3][t])
                  * 0.08838834764831845f;  // 1/sqrt(128)
        out[b*(MN+1) + c0 + t] = cmask[row] ? s : -100000.0f;
    }
}

extern "C" void kernel_launch(void* const* d_in, const int* in_sizes, int n_in,
                              void* d_out, int out_size, void* d_ws, size_t ws_size,
                              hipStream_t stream){
    (void)in_sizes; (void)n_in; (void)out_size; (void)ws_size;
    const int* start_entities      = (const int*)d_in[0];
    const int* aims                = (const int*)d_in[1];
    const int* node_pos            = (const int*)d_in[2];
    const int* neighbor_nodes      = (const int*)d_in[3];
    const int* neighbor_relations  = (const int*)d_in[4];
    const int* neighbors_num       = (const int*)d_in[5];
    const int* currents            = (const int*)d_in[6];
    const int* candidate_nodes     = (const int*)d_in[7];
    const int* candidate_entities  = (const int*)d_in[8];
    const int* candidate_relations = (const int*)d_in[9];
    const int* candidate_masks     = (const int*)d_in[10];
    const float* entity_emb   = (const float*)d_in[11];
    const float* relation_emb = (const float*)d_in[12];
    const float* hidden_W     = (const float*)d_in[13];
    const float* hidden_b     = (const float*)d_in[14];
    const float* pass_W       = (const float*)d_in[15];
    const float* pass_b       = (const float*)d_in[16];
    const float* nexthop_W    = (const float*)d_in[17];
    const float* nexthop_b    = (const float*)d_in[18];
    const float* candidate_W  = (const float*)d_in[19];
    const float* candidate_b  = (const float*)d_in[20];
    const float* gate_W       = (const float*)d_in[21];
    const float* gate_b       = (const float*)d_in[22];
    const float* query        = (const float*)d_in[23];
    float* out = (float*)d_out;

    float* ws     = (float*)d_ws;
    float* init   = ws;                        // B*H
    float* wninit = init + B*H;                // B*H
    float* upd    = wninit + B*H;              // B*K*H
    float* state  = upd + (long)B*K*H;         // B*H
    float* ab     = state + B*H;               // B*K*2
    float* zrow   = ab + B*K*2;                // 128
    int*   map    = (int*)(zrow + 128);        // B*NSLOT
    unsigned short* Wf    = (unsigned short*)(map + B*NSLOT);  // 49152
    unsigned short* Wcatf = Wf + 49152;                         // 32768
    unsigned short* Pf    = Wcatf + 32768;                      // 65536
    unsigned short* XhG   = Pf + 65536;                         // B*K*512
    unsigned short* XaG   = XhG + (long)B*K*512;                // B*K*128

    k_front<<<848 + (B*K)/4, 256, 0, stream>>>(aims, neighbor_nodes, neighbor_relations,
                                               neighbors_num, start_entities, node_pos,
                                               entity_emb, relation_emb,
                                               hidden_W, hidden_b, pass_W, candidate_W,
                                               ab, map, init, wninit, Wf, Wcatf,
                                               Pf, XhG, XaG, zrow);
    k_updg<<<B, 256, 0, stream>>>(XhG, XaG, ab, Wcatf, Pf, hidden_b, pass_b, wninit,
                                  currents, map, init, query,
                                  nexthop_W, nexthop_b, gate_W, gate_b,
                                  upd, state, out);
    k_cand<<<B*(MN/CTILE), 256, 0, stream>>>(candidate_nodes, candidate_entities,
                                             candidate_relations, candidate_masks,
                                             map, init, upd, entity_emb, relation_emb,
                                             Wf, candidate_b, state, zrow, out);
}

// Round 17
// 49.378 us; speedup vs baseline: 1.1050x; 1.0041x over previous
//
#include <hip/hip_runtime.h>

#define B 256
#define K 32
#define M 64
#define MN 256
#define E 128
#define H 128
#define Q 128
#define NSLOT 258   // NNODES+2
#define CTILE 32
#define XPAD 392    // 384 + 8 bf16 pad

typedef __attribute__((ext_vector_type(8))) short short8;
typedef __attribute__((ext_vector_type(4))) short short4b;
typedef __attribute__((ext_vector_type(4))) float f32x4;

__device__ __forceinline__ float lrelu(float x){ return x >= 0.f ? x : 0.01f*x; }

// fp32 -> bf16 RTNE
__device__ __forceinline__ unsigned short f2bf(float f){
    unsigned int u = __float_as_uint(f);
    unsigned int r = u + 0x7FFFu + ((u >> 16) & 1u);
    return (unsigned short)(r >> 16);
}

__device__ __forceinline__ short4b pack4(float4 v){
    short4b r;
    r.x = (short)f2bf(v.x); r.y = (short)f2bf(v.y);
    r.z = (short)f2bf(v.z); r.w = (short)f2bf(v.w);
    return r;
}

// load 8 consecutive fp32 and pack to bf16 short8
__device__ __forceinline__ short8 f8_from(const float* __restrict__ p){
    float4 u = *(const float4*)p;
    float4 v = *(const float4*)(p + 4);
    short8 s;
    s[0]=(short)f2bf(u.x); s[1]=(short)f2bf(u.y); s[2]=(short)f2bf(u.z); s[3]=(short)f2bf(u.w);
    s[4]=(short)f2bf(v.x); s[5]=(short)f2bf(v.y); s[6]=(short)f2bf(v.z); s[7]=(short)f2bf(v.w);
    return s;
}

// =====================================================================
// K_FRONT roles (by blockIdx):
//  blk <  256 : init[b] + wninit[b]
//  blk <  512 : RESOLVE role: per-b LDS map -> mvp[b][c] for all 256
//               candidates + mvcur[b] (kills the global map array)
//  blk <  704 : Wf  frag-order swizzle   (49152 elems)
//  blk <  832 : Wcatf frag-order swizzle (32768 elems; ks 4..7 = hW)
//  blk <  848 : P-build: P = rel_emb @ passW[:,H:]^T, frag-order Pf
//  else (2048): hist role: 4 bk per block
// =====================================================================
__global__ void k_front(const int* __restrict__ aims, const int* __restrict__ nbr_nodes,
                        const int* __restrict__ nbr_rels, const int* __restrict__ nbr_num,
                        const int* __restrict__ start_ent, const int* __restrict__ node_pos,
                        const int* __restrict__ cnodes, const int* __restrict__ currents,
                        const float* __restrict__ ent_emb, const float* __restrict__ rel_emb,
                        const float* __restrict__ hW, const float* __restrict__ hb,
                        const float* __restrict__ passW, const float* __restrict__ candW,
                        float* __restrict__ ab,
                        int* __restrict__ mvp, int* __restrict__ mvcur,
                        float* __restrict__ init_out, float* __restrict__ wninit_out,
                        unsigned short* __restrict__ Wf, unsigned short* __restrict__ Wcatf,
                        unsigned short* __restrict__ Pf,
                        unsigned short* __restrict__ XhG, unsigned short* __restrict__ XaG,
                        float* __restrict__ zrow){
    int blk = blockIdx.x, t = threadIdx.x;
    __shared__ float e[128];
    __shared__ float si[128];
    __shared__ unsigned int hist[4][512];
    __shared__ float sden[4];
    __shared__ int lmap[NSLOT];

    if (blk >= 848) {
        // ---------------- hist role: 4 bk per block ----------------
        int hb4 = blk - 848;
        for (int i = t; i < 2048; i += 256) ((unsigned int*)hist)[i] = 0u;
        __syncthreads();
        int w = t >> 6, lane = t & 63;
        int bk = hb4*4 + w;
        int num = nbr_num[bk];
        int nr  = nbr_rels[(long)bk*M + lane];
        int nn  = nbr_nodes[(long)bk*M + lane];
        unsigned long long mask = __ballot((lane < num) && (nn == 0));
        int c0 = (int)__popcll(mask);
        float denom = (float)(num > 0 ? num : 1);
        if (lane < num) atomicAdd(&hist[w][nr], 1u);
        float2 av = *(const float2*)&ent_emb[(long)aims[bk]*E + lane*2];
        ushort2 ap; ap.x = f2bf(av.x); ap.y = f2bf(av.y);
        *(ushort2*)&XaG[(long)bk*128 + lane*2] = ap;
        if (lane == 0) {
            ab[bk*2+0] = (float)c0 / denom;
            ab[bk*2+1] = (float)num / denom;
            sden[w] = 1.f / denom;
        }
        __syncthreads();
        for (int i = t; i < 2048; i += 256) {
            int w2 = i >> 9, r = i & 511;
            float v = (float)hist[w2][r] * sden[w2];
            XhG[((long)(hb4*4 + w2))*512 + r] = f2bf(v);
        }
        return;
    }

    int pb = blk;
    if (pb < 256) {
        int b = pb;
        if (t < 128) e[t] = ent_emb[(long)start_ent[b]*E + t];
        __syncthreads();
        if (t < 128) {
            float acc = hb[t];
            #pragma unroll 8
            for (int j=0;j<E;j++) acc += hW[t*E+j]*e[j];
            float v = lrelu(acc);
            si[t] = v;
            init_out[b*H+t] = v;
        }
        __syncthreads();
        if (t < 128) {
            float acc2 = 0.f;
            #pragma unroll 8
            for (int j=0;j<H;j++) acc2 += passW[t*(H+E)+j]*si[j];
            wninit_out[b*H+t] = acc2;
        }
    } else if (pb < 512) {
        // ---------------- resolve role: per-b candidate resolution ----------------
        int b = pb - 256;
        for (int i=t;i<NSLOT;i+=256) lmap[i] = -2;
        __syncthreads();
        if (t==0) lmap[0] = -1;
        __syncthreads();
        if (t<K) lmap[node_pos[b*K+t]] = t;
        if (pb == 256 && t >= 64 && t < 192) zrow[t-64] = 0.f;
        __syncthreads();
        mvp[b*MN + t] = lmap[cnodes[b*MN + t]];
        if (t == 0) mvcur[b] = lmap[currents[b]];
    } else if (pb < 704) {
        int i = (pb-512)*256 + t;       // < 49152
        int j = i & 7;
        int l = (i >> 3) & 63;
        int ct = (i >> 9) & 1;
        int r = i >> 10;                // 0..47
        int ks = r % 12, w = r / 12;
        int row = w*32 + ct*16 + (l & 15);
        int col = ks*32 + (l >> 4)*8 + j;
        Wf[i] = f2bf(candW[row*384 + col]);
    } else if (pb < 832) {
        int i = (pb-704)*256 + t;       // < 32768
        int j = i & 7;
        int l = (i >> 3) & 63;
        int ct = (i >> 9) & 1;
        int r = i >> 10;                // 0..31
        int ks = r & 7, w = r >> 3;
        int row = w*32 + ct*16 + (l & 15);
        int col = ks*32 + (l >> 4)*8 + j;
        float v = (col < 128) ? passW[row*256 + 128 + col] : hW[row*128 + (col-128)];
        Wcatf[i] = f2bf(v);
    } else {
        // ---------------- P-build: 16 blocks ----------------
        int g = pb - 832;               // 0..15
        int w = t >> 6, lane = t & 63;
        int l16 = lane & 15, lhi = lane >> 4;
        int hbase = w*32;
        const short8 z8 = (short8){0,0,0,0,0,0,0,0};
        f32x4 acc[2][2];
        #pragma unroll
        for (int rt=0;rt<2;rt++)
            #pragma unroll
            for (int ct=0;ct<2;ct++)
                acc[rt][ct] = (f32x4){0.f,0.f,0.f,0.f};
        #pragma unroll
        for (int ks2 = 0; ks2 < 4; ks2++) {
            int kof = ks2*32 + lhi*8;
            int r0 = g*32 + l16, r1 = g*32 + 16 + l16;
            short8 a0 = (r0 < 500) ? f8_from(&rel_emb[(long)r0*E + kof]) : z8;
            short8 a1 = (r1 < 500) ? f8_from(&rel_emb[(long)r1*E + kof]) : z8;
            short8 b0 = f8_from(&passW[(long)(hbase + l16)*(H+E) + H + kof]);
            short8 b1 = f8_from(&passW[(long)(hbase + 16 + l16)*(H+E) + H + kof]);
            acc[0][0] = __builtin_amdgcn_mfma_f32_16x16x32_bf16(a0, b0, acc[0][0], 0, 0, 0);
            acc[0][1] = __builtin_amdgcn_mfma_f32_16x16x32_bf16(a0, b1, acc[0][1], 0, 0, 0);
            acc[1][0] = __builtin_amdgcn_mfma_f32_16x16x32_bf16(a1, b0, acc[1][0], 0, 0, 0);
            acc[1][1] = __builtin_amdgcn_mfma_f32_16x16x32_bf16(a1, b1, acc[1][1], 0, 0, 0);
        }
        #pragma unroll
        for (int rt=0; rt<2; rt++) {
            #pragma unroll
            for (int ct=0; ct<2; ct++) {
                #pragma unroll
                for (int i=0;i<4;i++) {
                    int rp = rt*16 + 4*lhi + i;
                    long idx = ((long)((w*16 + g)*2 + ct))*512 + (l16 + (rp>>3)*16)*8 + (rp & 7);
                    Pf[idx] = f2bf(acc[rt][ct][i]);
                }
            }
        }
    }
}

// =====================================================================
// K_B: upd GEMM (hist@P^T + aimE@hW^T) + fused state/thresh
// =====================================================================
__global__ void k_updg(const unsigned short* __restrict__ XhG,
                       const unsigned short* __restrict__ XaG,
                       const float* __restrict__ ab,
                       const unsigned short* __restrict__ Wcatf,
                       const unsigned short* __restrict__ Pf,
                       const float* __restrict__ hb_, const float* __restrict__ passb,
                       const float* __restrict__ wninit,
                       const int* __restrict__ mvcur,
                       const float* __restrict__ init, const float* __restrict__ query,
                       const float* __restrict__ nW, const float* __restrict__ nb_,
                       const float* __restrict__ gW, const float* __restrict__ gb,
                       float* __restrict__ upd, float* __restrict__ state,
                       float* __restrict__ out){
    int b = blockIdx.x;
    int t = threadIdx.x;          // 0..255
    __shared__ __align__(16) unsigned short Xh[32][520];
    __shared__ __align__(16) unsigned short Xa[32][136];
    __shared__ float wni[128];
    __shared__ float sab[64];
    __shared__ float cc[H+Q];
    __shared__ float wsum[2];
    #pragma unroll
    for (int it = 0; it < 8; it++) {
        int idx = it*256 + t;
        int r = idx >> 6;
        int cg = (idx & 63) * 8;
        *(short8*)&Xh[r][cg] = *(const short8*)&XhG[((long)b*32 + r)*512 + cg];
    }
    #pragma unroll
    for (int it = 0; it < 2; it++) {
        int idx = it*256 + t;
        int r = idx >> 4;
        int cg = (idx & 15) * 8;
        *(short8*)&Xa[r][cg] = *(const short8*)&XaG[((long)b*32 + r)*128 + cg];
    }
    if (t < 128) wni[t] = wninit[b*128 + t];
    else if (t < 192) sab[t-128] = ab[b*64 + (t-128)];

    int w    = t >> 6;
    int lane = t & 63;
    int l16  = lane & 15;
    int lhi  = lane >> 4;
    int hbase = w*32;
    int mvc = mvcur[b];
    __syncthreads();

    f32x4 acc[2][2];
    #pragma unroll
    for (int rt=0;rt<2;rt++)
        #pragma unroll
        for (int ct=0;ct<2;ct++)
            acc[rt][ct] = (f32x4){0.f,0.f,0.f,0.f};

    #pragma unroll 4
    for (int ks = 0; ks < 16; ks++) {
        int kof = ks*32 + lhi*8;
        short8 a0 = *(const short8*)&Xh[l16][kof];
        short8 a1 = *(const short8*)&Xh[16 + l16][kof];
        short8 b0 = *(const short8*)&Pf[(((long)(w*16+ks)*2 + 0)*64 + lane)*8];
        short8 b1 = *(const short8*)&Pf[(((long)(w*16+ks)*2 + 1)*64 + lane)*8];
        acc[0][0] = __builtin_amdgcn_mfma_f32_16x16x32_bf16(a0, b0, acc[0][0], 0, 0, 0);
        acc[0][1] = __builtin_amdgcn_mfma_f32_16x16x32_bf16(a0, b1, acc[0][1], 0, 0, 0);
        acc[1][0] = __builtin_amdgcn_mfma_f32_16x16x32_bf16(a1, b0, acc[1][0], 0, 0, 0);
        acc[1][1] = __builtin_amdgcn_mfma_f32_16x16x32_bf16(a1, b1, acc[1][1], 0, 0, 0);
    }
    #pragma unroll
    for (int ks2 = 0; ks2 < 4; ks2++) {
        int kof = ks2*32 + lhi*8;
        short8 a0 = *(const short8*)&Xa[l16][kof];
        short8 a1 = *(const short8*)&Xa[16 + l16][kof];
        short8 b0 = *(const short8*)&Wcatf[((((w*8 + 4 + ks2)*2 + 0)*64) + lane)*8];
        short8 b1 = *(const short8*)&Wcatf[((((w*8 + 4 + ks2)*2 + 1)*64) + lane)*8];
        acc[0][0] = __builtin_amdgcn_mfma_f32_16x16x32_bf16(a0, b0, acc[0][0], 0, 0, 0);
        acc[0][1] = __builtin_amdgcn_mfma_f32_16x16x32_bf16(a0, b1, acc[0][1], 0, 0, 0);
        acc[1][0] = __builtin_amdgcn_mfma_f32_16x16x32_bf16(a1, b0, acc[1][0], 0, 0, 0);
        acc[1][1] = __builtin_amdgcn_mfma_f32_16x16x32_bf16(a1, b1, acc[1][1], 0, 0, 0);
    }

    int h0 = hbase + l16, h1 = hbase + 16 + l16;
    float hb0 = hb_[h0], hb1 = hb_[h1];
    float pb0 = passb[h0], pb1 = passb[h1];
    float w0 = wni[h0],  w1 = wni[h1];

    if (t < 128) {
        cc[t] = (mvc == -1) ? init[b*H + t] : 0.f;
        cc[H+t] = query[b*Q + t];
    }

    float uv[2][2][4];
    #pragma unroll
    for (int rt=0; rt<2; rt++) {
        #pragma unroll
        for (int i=0;i<4;i++) {
            int r = rt*16 + 4*lhi + i;
            float al = sab[r*2], be = sab[r*2+1];
            float v0 = lrelu(hb0 + al*w0 + be*pb0 + acc[rt][0][i]);
            float v1 = lrelu(hb1 + al*w1 + be*pb1 + acc[rt][1][i]);
            uv[rt][0][i] = v0; uv[rt][1][i] = v1;
            upd[((long)b*32 + r)*128 + h0] = v0;
            upd[((long)b*32 + r)*128 + h1] = v1;
        }
    }
    __syncthreads();
    if (mvc >= 0) {
        #pragma unroll
        for (int rt=0; rt<2; rt++) {
            #pragma unroll
            for (int i=0;i<4;i++) {
                int r = rt*16 + 4*lhi + i;
                if (r == mvc) { cc[h0] = uv[rt][0][i]; cc[h1] = uv[rt][1][i]; }
            }
        }
    }
    __syncthreads();

    if (t < 128) {
        float sacc = nb_[t];
        #pragma unroll 8
        for (int j=0;j<H+Q;j++) sacc += nW[t*(H+Q)+j]*cc[j];
        state[b*H+t] = lrelu(sacc);
        float tv = gW[t]*cc[t] + gW[H+t]*cc[H+t];
        for (int off=32; off>0; off>>=1) tv += __shfl_down(tv, off);
        if ((t&63)==0) wsum[t>>6] = tv;
    }
    __syncthreads();
    if (t==0) out[b*(MN+1) + MN] = wsum[0] + wsum[1] + gb[0];
}

// =====================================================================
// K_D: candidate linear, 2048 blocks x 32 cands; precomputed mvp
// (single-hop index chain) + branch-free batch staging (12 loads in
// flight), streamed weights, fused score.
// =====================================================================
__global__ void k_cand(const int* __restrict__ mvp, const int* __restrict__ cents,
                       const int* __restrict__ crels, const int* __restrict__ cmask,
                       const float* __restrict__ init, const float* __restrict__ upd,
                       const float* __restrict__ ent_emb, const float* __restrict__ rel_emb,
                       const unsigned short* __restrict__ Wf, const float* __restrict__ cb,
                       const float* __restrict__ state, const float* __restrict__ zrow,
                       float* __restrict__ out){
    int blk = blockIdx.x;          // 0..2047
    int b  = blk >> 3;
    int c0 = (blk & 7) * CTILE;
    int t  = threadIdx.x;          // 0..255

    __shared__ __align__(16) unsigned short Xb[CTILE][XPAD];
    __shared__ float sscore[4][CTILE];

    // ---- precomputed resolution + branch-free batch staging ----
    {
        int c8 = t >> 5;           // cand sub-slot 0..7
        int q  = t & 31;           // float4 index
        int mv[4], ce[4], cr[4];
        #pragma unroll
        for (int i = 0; i < 4; i++) {
            int row = b*MN + c0 + i*8 + c8;
            mv[i] = mvp[row];
            ce[i] = cents[row];
            cr[i] = crels[row];
        }
        const float* pn[4]; const float* pe[4]; const float* pr[4];
        #pragma unroll
        for (int i = 0; i < 4; i++) {
            const float* bs = zrow;                                  // mv == -2
            bs = (mv[i] == -1) ? (init + (long)b*H) : bs;
            bs = (mv[i] >= 0)  ? (upd + ((long)b*K + mv[i])*H) : bs;
            pn[i] = bs + q*4;
            pe[i] = ent_emb + (long)ce[i]*E + q*4;
            pr[i] = rel_emb + (long)cr[i]*E + q*4;
        }
        float4 vn[4], ve[4], vr[4];
        #pragma unroll
        for (int i = 0; i < 4; i++) vn[i] = *(const float4*)pn[i];
        #pragma unroll
        for (int i = 0; i < 4; i++) ve[i] = *(const float4*)pe[i];
        #pragma unroll
        for (int i = 0; i < 4; i++) vr[i] = *(const float4*)pr[i];
        #pragma unroll
        for (int i = 0; i < 4; i++) {
            int cl = i*8 + c8;
            *(short4b*)&Xb[cl][q*4]       = pack4(vn[i]);
            *(short4b*)&Xb[cl][128 + q*4] = pack4(ve[i]);
            *(short4b*)&Xb[cl][256 + q*4] = pack4(vr[i]);
        }
    }

    int w    = t >> 6;
    int lane = t & 63;
    int l16  = lane & 15;
    int lhi  = lane >> 4;

    float s0 = state[b*H + w*32 + l16];
    float s1 = state[b*H + w*32 + 16 + l16];
    float cb0 = cb[w*32 + l16];
    float cb1 = cb[w*32 + 16 + l16];
    __syncthreads();

    f32x4 acc[2][2];
    #pragma unroll
    for (int rt=0;rt<2;rt++)
        #pragma unroll
        for (int ct=0;ct<2;ct++)
            acc[rt][ct] = (f32x4){0.f,0.f,0.f,0.f};

    #pragma unroll
    for (int ks = 0; ks < 12; ks++) {
        int kof = ks*32 + lhi*8;
        short8 b0 = *(const short8*)&Wf[((((w*12+ks)*2+0)*64) + lane)*8];
        short8 b1 = *(const short8*)&Wf[((((w*12+ks)*2+1)*64) + lane)*8];
        short8 a0 = *(const short8*)&Xb[l16][kof];
        short8 a1 = *(const short8*)&Xb[16 + l16][kof];
        acc[0][0] = __builtin_amdgcn_mfma_f32_16x16x32_bf16(a0, b0, acc[0][0], 0, 0, 0);
        acc[0][1] = __builtin_amdgcn_mfma_f32_16x16x32_bf16(a0, b1, acc[0][1], 0, 0, 0);
        acc[1][0] = __builtin_amdgcn_mfma_f32_16x16x32_bf16(a1, b0, acc[1][0], 0, 0, 0);
        acc[1][1] = __builtin_amdgcn_mfma_f32_16x16x32_bf16(a1, b1, acc[1][1], 0, 0, 0);
    }

    #pragma unroll
    for (int rt=0; rt<2; rt++) {
        float ps[4];
        #pragma unroll
        for (int i=0;i<4;i++)
            ps[i] = lrelu(acc[rt][0][i] + cb0)*s0 + lrelu(acc[rt][1][i] + cb1)*s1;
        #pragma unroll
        for (int msk=1; msk<16; msk<<=1) {
            #pragma unroll
            for (int i=0;i<4;i++) ps[i] += __shfl_xor(ps[i], msk);
        }
        if (l16 == 0) {
            #pragma unroll
            for (int i=0;i<4;i++)
                sscore[w][rt*16 + 4*lhi + i] = ps[i];
        }
    }
    __syncthreads();

    if (t < CTILE) {
        int row = b*MN + c0 + t;
        float s = (sscore[0][t] + sscore[1][t] + sscore[2][t] + sscore[3][t])
                  * 0.08838834764831845f;  // 1/sqrt(128)
        out[b*(MN+1) + c0 + t] = cmask[row] ? s : -100000.0f;
    }
}

extern "C" void kernel_launch(void* const* d_in, const int* in_sizes, int n_in,
                              void* d_out, int out_size, void* d_ws, size_t ws_size,
                              hipStream_t stream){
    (void)in_sizes; (void)n_in; (void)out_size; (void)ws_size;
    const int* start_entities      = (const int*)d_in[0];
    const int* aims                = (const int*)d_in[1];
    const int* node_pos            = (const int*)d_in[2];
    const int* neighbor_nodes      = (const int*)d_in[3];
    const int* neighbor_relations  = (const int*)d_in[4];
    const int* neighbors_num       = (const int*)d_in[5];
    const int* currents            = (const int*)d_in[6];
    const int* candidate_nodes     = (const int*)d_in[7];
    const int* candidate_entities  = (const int*)d_in[8];
    const int* candidate_relations = (const int*)d_in[9];
    const int* candidate_masks     = (const int*)d_in[10];
    const float* entity_emb   = (const float*)d_in[11];
    const float* relation_emb = (const float*)d_in[12];
    const float* hidden_W     = (const float*)d_in[13];
    const float* hidden_b     = (const float*)d_in[14];
    const float* pass_W       = (const float*)d_in[15];
    const float* pass_b       = (const float*)d_in[16];
    const float* nexthop_W    = (const float*)d_in[17];
    const float* nexthop_b    = (const float*)d_in[18];
    const float* candidate_W  = (const float*)d_in[19];
    const float* candidate_b  = (const float*)d_in[20];
    const float* gate_W       = (const float*)d_in[21];
    const float* gate_b       = (const float*)d_in[22];
    const float* query        = (const float*)d_in[23];
    float* out = (float*)d_out;

    float* ws     = (float*)d_ws;
    float* init   = ws;                        // B*H
    float* wninit = init + B*H;                // B*H
    float* upd    = wninit + B*H;              // B*K*H
    float* state  = upd + (long)B*K*H;         // B*H
    float* ab     = state + B*H;               // B*K*2
    float* zrow   = ab + B*K*2;                // 128
    int*   mvp    = (int*)(zrow + 128);        // B*MN
    int*   mvcur  = mvp + B*MN;                // B
    unsigned short* Wf    = (unsigned short*)(mvcur + B);      // 49152
    unsigned short* Wcatf = Wf + 49152;                         // 32768
    unsigned short* Pf    = Wcatf + 32768;                      // 65536
    unsigned short* XhG   = Pf + 65536;                         // B*K*512
    unsigned short* XaG   = XhG + (long)B*K*512;                // B*K*128

    k_front<<<848 + (B*K)/4, 256, 0, stream>>>(aims, neighbor_nodes, neighbor_relations,
                                               neighbors_num, start_entities, node_pos,
                                               candidate_nodes, currents,
                                               entity_emb, relation_emb,
                                               hidden_W, hidden_b, pass_W, candidate_W,
                                               ab, mvp, mvcur, init, wninit, Wf, Wcatf,
                                               Pf, XhG, XaG, zrow);
    k_updg<<<B, 256, 0, stream>>>(XhG, XaG, ab, Wcatf, Pf, hidden_b, pass_b, wninit,
                                  mvcur, init, query,
                                  nexthop_W, nexthop_b, gate_W, gate_b,
                                  upd, state, out);
    k_cand<<<B*(MN/CTILE), 256, 0, stream>>>(mvp, candidate_entities,
                                             candidate_relations, candidate_masks,
                                             init, upd, entity_emb, relation_emb,
                                             Wf, candidate_b, state, zrow, out);
}